// Round 3
// baseline (40.665 us; speedup 1.0000x reference)
//
#include <hip/hip_runtime.h>

// out[b,o,c,l] = time[b,c,l] * sum_{i,k} W[o,i,c,k] * x[b,i,c,l+k-1]  (x zero-padded in l)
// b=16, i=64, c=4, L=4096, o=64, K=3
//
// Block = one (b, c, 64-l tile); 4 waves, each owns a 16-o strip.
// x staged to LDS transposed [row=l][col=i] bf16, XOR-swizzled (read-conflict-free).
// MFMA operand order: A = x (M=l), B = W (N=o)  ==>  D row = l, col = o, so the
// epilogue does float4 time-loads and float4 stores (l-contiguous per lane).

#define NB 16
#define NI 64
#define NC 4
#define NL 4096
#define NO 64
#define KW 3
#define LT 64             // l-tile per block
#define ROWS (LT + 2)     // l-halo of 1 each side
#define ROWB 128          // 64 i * 2B bf16 per LDS row

#define W_PACK_BYTES (NO * NI * NC * KW * 2)   // 98304

typedef float f32x4 __attribute__((ext_vector_type(4)));
typedef short bf16x8 __attribute__((ext_vector_type(8)));
typedef unsigned int u32x2 __attribute__((ext_vector_type(2)));

__device__ inline unsigned short f2bf(float f) {
    unsigned int u = __builtin_bit_cast(unsigned int, f);
    u += 0x7FFFu + ((u >> 16) & 1u);          // round-to-nearest-even
    return (unsigned short)(u >> 16);
}

// ---- kernel 1: pack W into per-lane fragment order (B operand: n=o in lane&15) ----
// flat bf16 index = (((c*4 + wv)*6 + cc)*64 + lane)*8 + j
// o = wv*16 + (lane&15), i = (cc&1)*32 + (lane>>4)*8 + j, k = cc>>1
__global__ __launch_bounds__(256)
void prepack_w_kernel(const float* __restrict__ w, unsigned short* __restrict__ wp) {
    const int idx  = blockIdx.x * 256 + threadIdx.x;     // 49152 total
    const int j    = idx & 7;
    const int lane = (idx >> 3) & 63;
    const int r9   = idx >> 9;                            // 0..95
    const int cc   = r9 % 6;
    const int wv   = (r9 / 6) & 3;
    const int c    = r9 / 24;
    const int orow = wv * 16 + (lane & 15);
    const int i    = (cc & 1) * 32 + ((lane >> 4) << 3) + j;
    const int k    = cc >> 1;
    wp[idx] = f2bf(w[((orow * NI + i) * NC + c) * KW + k]);
}

// ---- kernel 2: main ----
__global__ __launch_bounds__(256)
void tconv_mfma_kernel(const float* __restrict__ x,
                       const float* __restrict__ tt,
                       const unsigned short* __restrict__ wp,
                       float* __restrict__ out)
{
    __shared__ char lds[ROWS * ROWB];

    const int t    = threadIdx.x;
    const int lb   = blockIdx.x * LT;
    const int c    = blockIdx.y;
    const int b    = blockIdx.z;
    const int lane = t & 63;
    const int wave = t >> 6;
    const int o0   = wave * 16;

    // ---------- W fragments (B operand), 6 coalesced 16B loads ----------
    bf16x8 wfrag[6];
    {
        const bf16x8* wpb = (const bf16x8*)wp + (size_t)((c * 4 + wave) * 6) * 64 + lane;
#pragma unroll
        for (int cc = 0; cc < 6; ++cc) wfrag[cc] = wpb[cc * 64];
    }

    // ---------- stage x -> LDS: [row=l][col=i] bf16, 4 i per lane per iter, b64 writes ----------
    const float* xb = x + ((size_t)b * NI * NC + c) * NL;   // + i*NC*NL + l
    {
        const int rr = lane + 1;                             // rows 1..64
        const int l  = lb + lane;
        const int swz = (rr & 7) << 4;
#pragma unroll
        for (int it = 0; it < 4; ++it) {
            const int ib = (it * 4 + wave) * 4;              // 4 consecutive i
            const float* xi = xb + (size_t)ib * (NC * NL);
            const float a0 = xi[l];
            const float a1 = xi[(size_t)(NC * NL) + l];
            const float a2 = xi[(size_t)(2 * NC * NL) + l];
            const float a3 = xi[(size_t)(3 * NC * NL) + l];
            u32x2 pk;
            pk[0] = (unsigned int)f2bf(a0) | ((unsigned int)f2bf(a1) << 16);
            pk[1] = (unsigned int)f2bf(a2) | ((unsigned int)f2bf(a3) << 16);
            const int off = rr * ROWB + ((2 * ib) ^ swz);
            *(u32x2*)(lds + off) = pk;
        }
    }
    if (t < 128) {                                           // halo rows 0 and 65
        const int which = t & 1;
        const int i     = t >> 1;
        const int row   = which ? (LT + 1) : 0;
        const int l     = which ? (lb + LT) : (lb - 1);
        const bool ok   = (l >= 0) && (l < NL);
        const float v   = ok ? xb[(size_t)i * (NC * NL) + l] : 0.f;
        const int off = row * ROWB + ((2 * i) ^ ((row & 7) << 4));
        *(unsigned short*)(lds + off) = f2bf(v);
    }
    __syncthreads();

    // ---------- MFMA: A = x fragment (m=l in lane&15), B = W ----------
    f32x4 acc[LT / 16] = {};
    const int lcol  = lane & 15;
    const int ksub2 = (lane >> 4) * 16;                      // byte offset of k' chunk

#pragma unroll
    for (int lt = 0; lt < LT / 16; ++lt) {
#pragma unroll
        for (int cc = 0; cc < 6; ++cc) {
            const int k    = cc >> 1;
            const int ih   = cc & 1;
            const int row  = lt * 16 + lcol + k;
            const int colb = ih * 64 + ksub2;
            const int off  = row * ROWB + (colb ^ ((row & 7) << 4));
            const bf16x8 xfrag = *(const bf16x8*)(lds + off);
            acc[lt] = __builtin_amdgcn_mfma_f32_16x16x32_bf16(xfrag, wfrag[cc], acc[lt], 0, 0, 0);
        }
    }

    // ---------- epilogue: D row = l (4 consecutive per lane), col = o; float4 I/O ----------
    const float* tb = tt + (size_t)(b * NC + c) * NL;
    const int o  = o0 + lcol;
    float* orow = out + ((size_t)b * NO * NC + (size_t)o * NC + c) * NL;
#pragma unroll
    for (int lt = 0; lt < LT / 16; ++lt) {
        const int l0 = lb + lt * 16 + (lane >> 4) * 4;
        const f32x4 tv = *(const f32x4*)(tb + l0);
        f32x4 res;
#pragma unroll
        for (int r = 0; r < 4; ++r) res[r] = acc[lt][r] * tv[r];
        *(f32x4*)(orow + l0) = res;
    }
}

extern "C" void kernel_launch(void* const* d_in, const int* in_sizes, int n_in,
                              void* d_out, int out_size, void* d_ws, size_t ws_size,
                              hipStream_t stream) {
    const float* x  = (const float*)d_in[0];
    const float* tt = (const float*)d_in[1];
    const float* w  = (const float*)d_in[2];
    float* out = (float*)d_out;
    unsigned short* wpck = (unsigned short*)d_ws;

    dim3 block(256);
    prepack_w_kernel<<<dim3(NO * NI * NC * KW / 256), block, 0, stream>>>(w, wpck);

    dim3 grid(NL / LT, NC, NB);   // (64, 4, 16) = 4096 blocks
    tconv_mfma_kernel<<<grid, block, 0, stream>>>(x, tt, wpck, out);
}

// Round 4
// 37.325 us; speedup vs baseline: 1.0895x; 1.0895x over previous
//
#include <hip/hip_runtime.h>

// out[b,o,c,l] = time[b,c,l] * sum_{i,k} W[o,i,c,k] * x[b,i,c,l+k-1]  (x zero-padded in l)
// b=16, i=64, c=4, L=4096, o=64, K=3
//
// Block = one (b, c, 128-l range) processed as NT=2 tiles of LT=64 with LDS
// double-buffer; tile-1 global loads issue before tile-0 compute (T14 split).
// 4 waves, each owns a 16-o strip. x in LDS transposed [row=l][col=i] bf16,
// XOR-swizzled. MFMA: A=x (M=l), B=W (N=o) -> D row=l col=o, float4 epilogue.

#define NB 16
#define NI 64
#define NC 4
#define NL 4096
#define NO 64
#define KW 3
#define LT 64             // l-tile
#define NT 2              // tiles per block
#define ROWS (LT + 2)     // l-halo of 1 each side
#define ROWB 128          // 64 i * 2B bf16

#define W_PACK_BYTES (NO * NI * NC * KW * 2)   // 98304

typedef float f32x4 __attribute__((ext_vector_type(4)));
typedef short bf16x8 __attribute__((ext_vector_type(8)));
typedef unsigned int u32x2 __attribute__((ext_vector_type(2)));

__device__ inline unsigned short f2bf(float f) {
    unsigned int u = __builtin_bit_cast(unsigned int, f);
    u += 0x7FFFu + ((u >> 16) & 1u);          // round-to-nearest-even
    return (unsigned short)(u >> 16);
}

// ---- kernel 1: pack W. Coalesced READ (tid = w flat index), scattered 2B write.
// dest flat bf16 index = (((c*4 + wv)*6 + cc)*64 + lane)*8 + j  where
// o = wv*16 + (lane&15), i = (cc&1)*32 + (lane>>4)*8 + j, k = cc>>1
__global__ __launch_bounds__(256)
void prepack_w_kernel(const float* __restrict__ w, unsigned short* __restrict__ wp) {
    const int idx = blockIdx.x * 256 + threadIdx.x;      // 49152 = o*i*c*k
    const float v = w[idx];                              // coalesced
    const int k = idx % 3;
    int r = idx / 3;                                     // (o*64+i)*4 + c
    const int c = r & 3;  r >>= 2;                       // o*64 + i
    const int i = r & 63;
    const int o = r >> 6;
    const int cc   = k * 2 + (i >> 5);
    const int lane = (((i >> 3) & 3) << 4) | (o & 15);
    const int j    = i & 7;
    const int wv   = o >> 4;
    wp[(((c * 4 + wv) * 6 + cc) * 64 + lane) * 8 + j] = f2bf(v);
}

// ---- main ----
__device__ __forceinline__ void load_x(const float* __restrict__ xb, int lb,
                                       int t, int lane, int wave,
                                       float s[16], float& h) {
    const int l = lb + lane;
#pragma unroll
    for (int it = 0; it < 4; ++it) {
        const int ib = (it * 4 + wave) * 4;              // 4 consecutive i
        const float* xi = xb + (size_t)ib * (NC * NL);
        s[it * 4 + 0] = xi[l];
        s[it * 4 + 1] = xi[(size_t)(NC * NL) + l];
        s[it * 4 + 2] = xi[(size_t)(2 * NC * NL) + l];
        s[it * 4 + 3] = xi[(size_t)(3 * NC * NL) + l];
    }
    h = 0.f;
    if (t < 128) {                                       // halo rows 0 and 65
        const int which = t & 1;
        const int i     = t >> 1;
        const int lh    = which ? (lb + LT) : (lb - 1);
        if (lh >= 0 && lh < NL) h = xb[(size_t)i * (NC * NL) + lh];
    }
}

__device__ __forceinline__ void write_lds(char* __restrict__ buf,
                                          int t, int lane, int wave,
                                          const float s[16], float h) {
    const int rr  = lane + 1;                            // rows 1..64
    const int swz = (rr & 7) << 4;
#pragma unroll
    for (int it = 0; it < 4; ++it) {
        const int ib = (it * 4 + wave) * 4;
        u32x2 pk;
        pk[0] = (unsigned int)f2bf(s[it * 4 + 0]) | ((unsigned int)f2bf(s[it * 4 + 1]) << 16);
        pk[1] = (unsigned int)f2bf(s[it * 4 + 2]) | ((unsigned int)f2bf(s[it * 4 + 3]) << 16);
        *(u32x2*)(buf + rr * ROWB + ((2 * ib) ^ swz)) = pk;
    }
    if (t < 128) {
        const int which = t & 1;
        const int i     = t >> 1;
        const int row   = which ? (LT + 1) : 0;
        *(unsigned short*)(buf + row * ROWB + ((2 * i) ^ ((row & 7) << 4))) = f2bf(h);
    }
}

__device__ __forceinline__ void compute_store(const char* __restrict__ buf,
                                              const bf16x8 wfrag[6],
                                              const float* __restrict__ tb,
                                              float* __restrict__ ob,
                                              int lb, int lane) {
    const int lcol  = lane & 15;
    const int ksub2 = (lane >> 4) * 16;

    f32x4 tv[4];                                         // hoisted time loads
#pragma unroll
    for (int lt = 0; lt < 4; ++lt)
        tv[lt] = *(const f32x4*)(tb + lb + lt * 16 + (lane >> 4) * 4);

    f32x4 acc[4] = {};
#pragma unroll
    for (int lt = 0; lt < 4; ++lt) {
#pragma unroll
        for (int cc = 0; cc < 6; ++cc) {
            const int k    = cc >> 1;
            const int ih   = cc & 1;
            const int row  = lt * 16 + lcol + k;
            const int colb = ih * 64 + ksub2;
            const int off  = row * ROWB + (colb ^ ((row & 7) << 4));
            const bf16x8 xf = *(const bf16x8*)(buf + off);
            acc[lt] = __builtin_amdgcn_mfma_f32_16x16x32_bf16(xf, wfrag[cc], acc[lt], 0, 0, 0);
        }
    }
#pragma unroll
    for (int lt = 0; lt < 4; ++lt) {
        const int l0 = lb + lt * 16 + (lane >> 4) * 4;
        f32x4 r;
#pragma unroll
        for (int q = 0; q < 4; ++q) r[q] = acc[lt][q] * tv[lt][q];
        *(f32x4*)(ob + l0) = r;
    }
}

__global__ __launch_bounds__(256)
void tconv_mfma_kernel(const float* __restrict__ x,
                       const float* __restrict__ tt,
                       const unsigned short* __restrict__ wp,
                       float* __restrict__ out)
{
    __shared__ char lds[NT][ROWS * ROWB];

    const int t    = threadIdx.x;
    const int lane = t & 63;
    const int wave = t >> 6;
    const int c    = blockIdx.y;
    const int b    = blockIdx.z;
    const int lb0  = blockIdx.x * (LT * NT);
    const int lb1  = lb0 + LT;
    const int o0   = wave * 16;

    // W fragments (B operand): 6 coalesced 16B loads, L2-resident
    bf16x8 wfrag[6];
    {
        const bf16x8* wpb = (const bf16x8*)wp + (size_t)((c * 4 + wave) * 6) * 64 + lane;
#pragma unroll
        for (int cc = 0; cc < 6; ++cc) wfrag[cc] = wpb[cc * 64];
    }

    const float* xb = x + ((size_t)b * NI * NC + c) * NL;
    const float* tb = tt + (size_t)(b * NC + c) * NL;
    float* ob = out + ((size_t)b * NO * NC + (size_t)(o0 + (lane & 15)) * NC + c) * NL;

    // ---- tile 0: load, write, sync
    float s0[16], h0;
    load_x(xb, lb0, t, lane, wave, s0, h0);
    write_lds(&lds[0][0], t, lane, wave, s0, h0);
    __syncthreads();

    // ---- tile 1 loads issue NOW (hide under tile-0 compute)
    float s1[16], h1;
    load_x(xb, lb1, t, lane, wave, s1, h1);

    // ---- tile 0 compute + store (tile-1 loads in flight)
    compute_store(&lds[0][0], wfrag, tb, ob, lb0, lane);

    // ---- tile 1: write (waits on its loads), sync, compute
    write_lds(&lds[1][0], t, lane, wave, s1, h1);
    __syncthreads();
    compute_store(&lds[1][0], wfrag, tb, ob, lb1, lane);
}

extern "C" void kernel_launch(void* const* d_in, const int* in_sizes, int n_in,
                              void* d_out, int out_size, void* d_ws, size_t ws_size,
                              hipStream_t stream) {
    const float* x  = (const float*)d_in[0];
    const float* tt = (const float*)d_in[1];
    const float* w  = (const float*)d_in[2];
    float* out = (float*)d_out;
    unsigned short* wpck = (unsigned short*)d_ws;

    dim3 block(256);
    prepack_w_kernel<<<dim3(NO * NI * NC * KW / 256), block, 0, stream>>>(w, wpck);

    dim3 grid(NL / (LT * NT), NC, NB);   // (32, 4, 16) = 2048 blocks
    tconv_mfma_kernel<<<grid, block, 0, stream>>>(x, tt, wpck, out);
}

// Round 5
// 33.596 us; speedup vs baseline: 1.2104x; 1.1110x over previous
//
#include <hip/hip_runtime.h>

// out[b,o,c,l] = time[b,c,l] * sum_{i,k} W[o,i,c,k] * x[b,i,c,l+k-1]  (x zero-padded in l)
// b=16, i=64, c=4, L=4096, o=64, K=3
//
// Block = one (b, c, 256-l range): 4 chunks of 64 l in ONE contiguous LDS
// buffer of 258 rows ([row = l - (lb0-1)][col = i] bf16, XOR-swizzled), so
// inter-chunk halos are free. Stage-ahead-by-one pipeline (compute(t) reads
// into chunk t+1's first row): loads for chunk t+2 issue before compute(t),
// LDS-write after (T14). Staging: 4 x dwordx4 loads (4 i-planes, same l-quad),
// 4x4 register transpose, 4 x ds_write_b64. MFMA A=x, B=W -> D row=l col=o,
// float4 epilogue. Grid 1024 = 256 CU x 4 blocks, one residency round.

#define NB 16
#define NI 64
#define NC 4
#define NL 4096
#define NO 64
#define KW 3
#define LT 64
#define NT 4
#define LBLK (LT * NT)        // 256 l per block
#define ROWS (LBLK + 2)       // 258
#define ROWB 128              // 64 i * 2B

#define W_PACK_BYTES (NO * NI * NC * KW * 2)   // 98304

typedef float f32x4 __attribute__((ext_vector_type(4)));
typedef short bf16x8 __attribute__((ext_vector_type(8)));
typedef unsigned int u32x2 __attribute__((ext_vector_type(2)));

__device__ inline unsigned short f2bf(float f) {
    unsigned int u = __builtin_bit_cast(unsigned int, f);
    u += 0x7FFFu + ((u >> 16) & 1u);          // round-to-nearest-even
    return (unsigned short)(u >> 16);
}

// ---- kernel 1: pack W. Coalesced READ (tid = w flat index), scattered 2B write.
// dest flat bf16 index = (((c*4 + wv)*6 + cc)*64 + lane)*8 + j  where
// o = wv*16 + (lane&15), i = (cc&1)*32 + (lane>>4)*8 + j, k = cc>>1
__global__ __launch_bounds__(256)
void prepack_w_kernel(const float* __restrict__ w, unsigned short* __restrict__ wp) {
    const int idx = blockIdx.x * 256 + threadIdx.x;      // 49152 = o*i*c*k
    const float v = w[idx];                              // coalesced
    const int k = idx % 3;
    int r = idx / 3;
    const int c = r & 3;  r >>= 2;
    const int i = r & 63;
    const int o = r >> 6;
    const int cc   = k * 2 + (i >> 5);
    const int lane = (((i >> 3) & 3) << 4) | (o & 15);
    const int j    = i & 7;
    const int wv   = o >> 4;
    wp[(((c * 4 + wv) * 6 + cc) * 64 + lane) * 8 + j] = f2bf(v);
}

// ---- main ----
// staging task: quad = lane&15 (l-quad), g = wave*4 + (lane>>4) (i-group of 4)
__device__ __forceinline__ void stage_load(const float* __restrict__ xb,
                                           int l0, int g, f32x4 s[4]) {
    const float* p = xb + (size_t)(4 * g) * (NC * NL) + l0;
    s[0] = *(const f32x4*)(p);
    s[1] = *(const f32x4*)(p + NC * NL);
    s[2] = *(const f32x4*)(p + 2 * NC * NL);
    s[3] = *(const f32x4*)(p + 3 * NC * NL);
}

__device__ __forceinline__ void stage_write(char* __restrict__ lds,
                                            int r0, int g, const f32x4 s[4]) {
#pragma unroll
    for (int r = 0; r < 4; ++r) {
        const int rr = r0 + r;
        u32x2 pk;
        pk[0] = (unsigned int)f2bf(s[0][r]) | ((unsigned int)f2bf(s[1][r]) << 16);
        pk[1] = (unsigned int)f2bf(s[2][r]) | ((unsigned int)f2bf(s[3][r]) << 16);
        *(u32x2*)(lds + rr * ROWB + ((8 * g) ^ ((rr & 7) << 4))) = pk;
    }
}

__device__ __forceinline__ void compute_store(const char* __restrict__ lds,
                                              const bf16x8 wfrag[6],
                                              const float* __restrict__ tb,
                                              float* __restrict__ ob,
                                              int t, int lb0, int lane) {
    const int lcol  = lane & 15;
    const int ksub2 = (lane >> 4) * 16;
    const int lbt   = lb0 + t * LT;

    f32x4 tv[4];
#pragma unroll
    for (int lt = 0; lt < 4; ++lt)
        tv[lt] = *(const f32x4*)(tb + lbt + lt * 16 + (lane >> 4) * 4);

    f32x4 acc[4] = {};
#pragma unroll
    for (int lt = 0; lt < 4; ++lt) {
#pragma unroll
        for (int cc = 0; cc < 6; ++cc) {
            const int k    = cc >> 1;
            const int ih   = cc & 1;
            const int row  = t * LT + lt * 16 + lcol + k;
            const int colb = ih * 64 + ksub2;
            const int off  = row * ROWB + (colb ^ ((row & 7) << 4));
            const bf16x8 xf = *(const bf16x8*)(lds + off);
            acc[lt] = __builtin_amdgcn_mfma_f32_16x16x32_bf16(xf, wfrag[cc], acc[lt], 0, 0, 0);
        }
    }
#pragma unroll
    for (int lt = 0; lt < 4; ++lt) {
        const int l0 = lbt + lt * 16 + (lane >> 4) * 4;
        f32x4 r;
#pragma unroll
        for (int q = 0; q < 4; ++q) r[q] = acc[lt][q] * tv[lt][q];
        *(f32x4*)(ob + l0) = r;
    }
}

__global__ __launch_bounds__(256, 4)
void tconv_mfma_kernel(const float* __restrict__ x,
                       const float* __restrict__ tt,
                       const unsigned short* __restrict__ wp,
                       float* __restrict__ out)
{
    __shared__ char lds[ROWS * ROWB];                    // 33 024 B

    const int t    = threadIdx.x;
    const int lane = t & 63;
    const int wave = t >> 6;
    const int c    = blockIdx.y;
    const int b    = blockIdx.z;
    const int lb0  = blockIdx.x * LBLK;
    const int o0   = wave * 16;
    const int quad = lane & 15;
    const int g    = wave * 4 + (lane >> 4);
    const int lq   = 4 * quad;                           // l offset of this lane's quad

    // W fragments (B operand): 6 coalesced 16B loads, L2-resident
    bf16x8 wfrag[6];
    {
        const bf16x8* wpb = (const bf16x8*)wp + (size_t)((c * 4 + wave) * 6) * 64 + lane;
#pragma unroll
        for (int cc = 0; cc < 6; ++cc) wfrag[cc] = wpb[cc * 64];
    }

    const float* xb = x + ((size_t)b * NI * NC + c) * NL;
    const float* tb = tt + (size_t)(b * NC + c) * NL;
    float* ob = out + ((size_t)b * NO * NC + (size_t)(o0 + (lane & 15)) * NC + c) * NL;

    // ---- prologue: chunks 0,1 + halo rows 0 & 257
    f32x4 s0[4], s1[4];
    stage_load(xb, lb0 + 0 * LT + lq, g, s0);
    stage_load(xb, lb0 + 1 * LT + lq, g, s1);
    float h = 0.f; int hrow = 0, hcol = 0;
    if (t < 128) {
        const int which = t & 1;
        const int i     = t >> 1;
        hrow = which ? (LBLK + 1) : 0;
        hcol = 2 * i;
        const int lh = which ? (lb0 + LBLK) : (lb0 - 1);
        if (lh >= 0 && lh < NL) h = xb[(size_t)i * (NC * NL) + lh];
    }
    stage_write(lds, 1 + 0 * LT + lq, g, s0);
    stage_write(lds, 1 + 1 * LT + lq, g, s1);
    if (t < 128)
        *(unsigned short*)(lds + hrow * ROWB + (hcol ^ ((hrow & 7) << 4))) = f2bf(h);
    __syncthreads();

    // ---- steady state: compute(t) needs chunk t+1; stage chunk t+2 around it
    stage_load(xb, lb0 + 2 * LT + lq, g, s0);            // chunk 2 loads in flight
    compute_store(lds, wfrag, tb, ob, 0, lb0, lane);
    stage_write(lds, 1 + 2 * LT + lq, g, s0);
    __syncthreads();

    stage_load(xb, lb0 + 3 * LT + lq, g, s1);            // chunk 3 loads in flight
    compute_store(lds, wfrag, tb, ob, 1, lb0, lane);
    stage_write(lds, 1 + 3 * LT + lq, g, s1);
    __syncthreads();

    // ---- drain
    compute_store(lds, wfrag, tb, ob, 2, lb0, lane);
    compute_store(lds, wfrag, tb, ob, 3, lb0, lane);
}

extern "C" void kernel_launch(void* const* d_in, const int* in_sizes, int n_in,
                              void* d_out, int out_size, void* d_ws, size_t ws_size,
                              hipStream_t stream) {
    const float* x  = (const float*)d_in[0];
    const float* tt = (const float*)d_in[1];
    const float* w  = (const float*)d_in[2];
    float* out = (float*)d_out;
    unsigned short* wpck = (unsigned short*)d_ws;

    dim3 block(256);
    prepack_w_kernel<<<dim3(NO * NI * NC * KW / 256), block, 0, stream>>>(w, wpck);

    dim3 grid(NL / LBLK, NC, NB);   // (16, 4, 16) = 1024 blocks
    tconv_mfma_kernel<<<grid, block, 0, stream>>>(x, tt, wpck, out);
}